// Round 1
// baseline (2686.310 us; speedup 1.0000x reference)
//
#include <hip/hip_runtime.h>
#include <hip/hip_bf16.h>
#include <math.h>

#define B_   128
#define FQ_  318
#define CH0_ 109
#define NN_  1024
#define MM_  1025
#define C1_  512
#define C2_  256
#define C3_  128

// ---------------------------------------------------------------------------
// Encoder: t0[b, m, c] = sum_f x[b, f, m] * Wenc[c, f] + benc[c];  row m==0 -> 0
// t0 layout: (B, 1025, 109) node-major so the next layer's gather is coalesced.
// ---------------------------------------------------------------------------
__global__ __launch_bounds__(256) void enc_kernel(
    const float* __restrict__ x, const float* __restrict__ Wenc,
    const float* __restrict__ benc, float* __restrict__ t0)
{
    __shared__ __align__(16) float Xs[16][68];   // [f_local][m_local]
    __shared__ __align__(16) float WsT[16][68];  // [f_local][c_local]

    const int tid = threadIdx.x;
    const int b  = blockIdx.z;
    const int m0 = blockIdx.x * 64;
    const int c0 = blockIdx.y * 64;
    const int txc = tid & 15;   // 16 groups x 4 c
    const int tym = tid >> 4;   // 16 groups x 4 m

    float acc[4][4];
#pragma unroll
    for (int i = 0; i < 4; ++i)
#pragma unroll
        for (int j = 0; j < 4; ++j) acc[i][j] = 0.f;

    const int ml = tid & 63;
    const int kq = tid >> 6;
    const int wl = tid & 15;
    const int wg = tid >> 4;

    for (int f0 = 0; f0 < FQ_; f0 += 16) {
        // X tile: coalesced over m
#pragma unroll
        for (int i = 0; i < 4; ++i) {
            const int k = kq * 4 + i;
            const int f = f0 + k;
            const int m = m0 + ml;
            Xs[k][ml] = (f < FQ_ && m < MM_)
                        ? x[(size_t)b * FQ_ * MM_ + (size_t)f * MM_ + m] : 0.f;
        }
        // W tile (transposed): WsT[f_local][c_local]
#pragma unroll
        for (int pass = 0; pass < 4; ++pass) {
            const int cl = pass * 16 + wg;
            const int f  = f0 + wl;
            WsT[wl][cl] = (c0 + cl < CH0_ && f < FQ_)
                          ? Wenc[(size_t)(c0 + cl) * FQ_ + f] : 0.f;
        }
        __syncthreads();
#pragma unroll
        for (int k = 0; k < 16; ++k) {
            const float4 a = *reinterpret_cast<const float4*>(&Xs[k][tym * 4]);
            const float4 w = *reinterpret_cast<const float4*>(&WsT[k][txc * 4]);
            const float av[4] = {a.x, a.y, a.z, a.w};
            const float wv[4] = {w.x, w.y, w.z, w.w};
#pragma unroll
            for (int i = 0; i < 4; ++i)
#pragma unroll
                for (int j = 0; j < 4; ++j)
                    acc[i][j] = fmaf(av[i], wv[j], acc[i][j]);
        }
        __syncthreads();
    }

#pragma unroll
    for (int i = 0; i < 4; ++i) {
        const int m = m0 + tym * 4 + i;
        if (m >= MM_) continue;
#pragma unroll
        for (int j = 0; j < 4; ++j) {
            const int c = c0 + txc * 4 + j;
            if (c >= CH0_) continue;
            const float v = (m == 0) ? 0.f : (acc[i][j] + benc[c]);
            t0[((size_t)b * MM_ + m) * CH0_ + c] = v;
        }
    }
}

// ---------------------------------------------------------------------------
// Gather-conv layer (per-batch GEMM with on-the-fly gather + optional fused
// normalization of the *input*), plus per-batch sum/sumsq stats of the raw
// output (for the next layer's TreeLayerNorm).
//   out[b, n+1, o] = bias[o] + sum_{c,k} normIn(tin[b, idx[b,3n+k], c]) * W[o,c,k]
//   out[b, 0, :]   = 0
// Layouts: tin (B,1025,C_IN) node-major, tout (B,1025,C_OUT) node-major,
//          W (C_OUT, C_IN, 3) => flat [o][j], j = 3c+k.
// ---------------------------------------------------------------------------
template <int C_IN, int C_OUT, bool NORM>
__global__ __launch_bounds__(256) void conv_kernel(
    const float* __restrict__ tin, const int* __restrict__ idx,
    const float* __restrict__ W, const float* __restrict__ bias,
    const double* __restrict__ stats_in, const int prev_count,
    double* __restrict__ stats_out, float* __restrict__ tout)
{
    constexpr int K3 = 3 * C_IN;
    __shared__ __align__(16) float Gs[24][132];   // [j_local][n_local]
    __shared__ __align__(16) float Ws[24][132];   // [j_local][o_local]
    __shared__ int idxs[384];
    __shared__ float s_norm[2];
    __shared__ double redS[4], redQ[4];

    const int tid = threadIdx.x;
    const int b  = blockIdx.z;
    const int n0 = blockIdx.x * 128;
    const int o0 = blockIdx.y * 128;

    {   // idx triples for the 128 nodes of this tile
        const int* ip = idx + (size_t)b * (3 * NN_) + n0 * 3;
        idxs[tid] = ip[tid];
        if (tid < 128) idxs[256 + tid] = ip[256 + tid];
    }
    if (NORM && tid == 0) {
        const double s = stats_in[2 * b], q = stats_in[2 * b + 1];
        const double mean = s / prev_count;
        const double var  = (q - s * s / prev_count) / (prev_count - 1);
        s_norm[0] = (float)mean;
        s_norm[1] = (float)(1.0 / (sqrt(var) + 1e-5));
    }
    __syncthreads();
    const float mean = NORM ? s_norm[0] : 0.f;
    const float inv  = NORM ? s_norm[1] : 0.f;

    const int txo = tid & 15;   // 16 groups x 8 o
    const int tyn = tid >> 4;   // 16 groups x 8 n

    float acc[8][8];
#pragma unroll
    for (int i = 0; i < 8; ++i)
#pragma unroll
        for (int j = 0; j < 8; ++j) acc[i][j] = 0.f;

    const float* tb = tin + (size_t)b * MM_ * C_IN;
    const int gl = tid & 7;   // c lane within 8-wide run
    const int gg = tid >> 3;  // 32 gather groups
    const int wol = tid >> 1; // 128 o rows
    const int wh  = tid & 1;  // half of the 24-wide j run

    const int nChunks = (C_IN + 7) / 8;
    for (int cc = 0; cc < nChunks; ++cc) {
        const int c0 = cc * 8;
        const int j0 = c0 * 3;
        // ---- G tile: gather 8 contiguous c's per (n, k) pair ----
#pragma unroll
        for (int pass = 0; pass < 12; ++pass) {
            const int p  = pass * 32 + gg;   // pair = kk*128 + n
            const int kk = p >> 7;
            const int n  = p & 127;
            const int jcol = idxs[n * 3 + kk];
            const int c = c0 + gl;
            float v = 0.f;
            if ((C_IN % 8 == 0) || (c < C_IN)) {
                v = tb[(size_t)jcol * C_IN + c];
                if (NORM) v = fmaxf(0.f, (v - mean) * inv);
            }
            Gs[gl * 3 + kk][n] = v;
        }
        // ---- W tile (transposed) ----
        {
            const int jb = j0 + wh * 12;
            const float* wp = W + (size_t)(o0 + wol) * K3 + jb;
#pragma unroll
            for (int i = 0; i < 12; ++i) {
                float w = 0.f;
                if ((K3 % 24 == 0) || (jb + i < K3)) w = wp[i];
                Ws[wh * 12 + i][wol] = w;
            }
        }
        __syncthreads();
#pragma unroll 6
        for (int k = 0; k < 24; ++k) {
            const float4 a0 = *reinterpret_cast<const float4*>(&Gs[k][tyn * 8]);
            const float4 a1 = *reinterpret_cast<const float4*>(&Gs[k][tyn * 8 + 4]);
            const float4 w0 = *reinterpret_cast<const float4*>(&Ws[k][txo * 8]);
            const float4 w1 = *reinterpret_cast<const float4*>(&Ws[k][txo * 8 + 4]);
            const float av[8] = {a0.x, a0.y, a0.z, a0.w, a1.x, a1.y, a1.z, a1.w};
            const float wv[8] = {w0.x, w0.y, w0.z, w0.w, w1.x, w1.y, w1.z, w1.w};
#pragma unroll
            for (int i = 0; i < 8; ++i)
#pragma unroll
                for (int j = 0; j < 8; ++j)
                    acc[i][j] = fmaf(av[i], wv[j], acc[i][j]);
        }
        __syncthreads();
    }

    // ---- epilogue: bias, store raw, accumulate stats ----
    float bv[8];
#pragma unroll
    for (int j = 0; j < 8; ++j) bv[j] = bias[o0 + txo * 8 + j];

    double s = 0.0, q = 0.0;
    float* outb = tout + (size_t)b * MM_ * C_OUT;
#pragma unroll
    for (int i = 0; i < 8; ++i) {
        const int n = n0 + tyn * 8 + i;          // 0..1023 -> row n+1
        float* rowp = outb + (size_t)(n + 1) * C_OUT + o0 + txo * 8;
        float vals[8];
#pragma unroll
        for (int j = 0; j < 8; ++j) {
            const float v = acc[i][j] + bv[j];
            vals[j] = v;
            s += (double)v;
            q += (double)v * (double)v;
        }
        *reinterpret_cast<float4*>(rowp)     = make_float4(vals[0], vals[1], vals[2], vals[3]);
        *reinterpret_cast<float4*>(rowp + 4) = make_float4(vals[4], vals[5], vals[6], vals[7]);
    }
    if (n0 == 0 && tid < 128) {                  // null-slot row 0 = 0 (pre-norm)
        outb[o0 + tid] = 0.f;
    }
    // block reduction of stats, then 2 atomics
#pragma unroll
    for (int off = 32; off > 0; off >>= 1) {
        s += __shfl_down(s, off);
        q += __shfl_down(q, off);
    }
    const int lane = tid & 63, wid = tid >> 6;
    if (lane == 0) { redS[wid] = s; redQ[wid] = q; }
    __syncthreads();
    if (tid == 0) {
        const double ts = redS[0] + redS[1] + redS[2] + redS[3];
        const double tq = redQ[0] + redQ[1] + redQ[2] + redQ[3];
        atomicAdd(&stats_out[2 * b], ts);
        atomicAdd(&stats_out[2 * b + 1], tq);
    }
}

// ---------------------------------------------------------------------------
// Fused: normalize t3 on the fly, max-pool over 1025 nodes, then the MLP head.
// One block per batch, 128 threads.
// ---------------------------------------------------------------------------
__global__ __launch_bounds__(128) void pool_head_kernel(
    const float* __restrict__ t3, const double* __restrict__ stats3,
    const float* __restrict__ Wh1, const float* __restrict__ bh1,
    const float* __restrict__ Wh2, const float* __restrict__ bh2,
    const float* __restrict__ Wh3, const float* __restrict__ bh3,
    const float* __restrict__ Wh4, const float* __restrict__ bh4,
    float* __restrict__ out)
{
    __shared__ float hs[128], h1s[128], h2s[64], h3s[32];
    const int b = blockIdx.x, o = threadIdx.x;

    const double ssum = stats3[2 * b], ssq = stats3[2 * b + 1];
    const double cnt  = (double)C3_ * (double)MM_;
    const double meand = ssum / cnt;
    const double var   = (ssq - ssum * ssum / cnt) / (cnt - 1.0);
    const float mean = (float)meand;
    const float inv  = (float)(1.0 / (sqrt(var) + 1e-5));

    const float* tb = t3 + (size_t)b * MM_ * C3_;
    float best = 0.f;   // relu'd values are >= 0
    for (int m = 0; m < MM_; ++m) {
        const float v = fmaxf(0.f, (tb[(size_t)m * C3_ + o] - mean) * inv);
        best = fmaxf(best, v);
    }
    hs[o] = best;
    __syncthreads();

    float a1 = bh1[o];
    for (int i = 0; i < 128; ++i) a1 = fmaf(Wh1[o * 128 + i], hs[i], a1);
    h1s[o] = fmaxf(a1, 0.f);
    __syncthreads();

    if (o < 64) {
        float a2 = bh2[o];
        for (int i = 0; i < 128; ++i) a2 = fmaf(Wh2[o * 128 + i], h1s[i], a2);
        h2s[o] = fmaxf(a2, 0.f);
    }
    __syncthreads();

    if (o < 32) {
        float a3 = bh3[o];
        for (int i = 0; i < 64; ++i) a3 = fmaf(Wh3[o * 64 + i], h2s[i], a3);
        h3s[o] = fmaxf(a3, 0.f);
    }
    __syncthreads();

    if (o == 0) {
        float a4 = bh4[0];
        for (int i = 0; i < 32; ++i) a4 = fmaf(Wh4[i], h3s[i], a4);
        out[b] = a4;
    }
}

// ---------------------------------------------------------------------------
extern "C" void kernel_launch(void* const* d_in, const int* in_sizes, int n_in,
                              void* d_out, int out_size, void* d_ws, size_t ws_size,
                              hipStream_t stream)
{
    const float* x    = (const float*)d_in[0];
    const int*   idx  = (const int*)d_in[1];
    const float* Wenc = (const float*)d_in[2];
    const float* benc = (const float*)d_in[3];
    const float* W1   = (const float*)d_in[4];
    const float* b1   = (const float*)d_in[5];
    const float* W2   = (const float*)d_in[6];
    const float* b2   = (const float*)d_in[7];
    const float* W3   = (const float*)d_in[8];
    const float* b3   = (const float*)d_in[9];
    const float* Wh1  = (const float*)d_in[10];
    const float* bh1  = (const float*)d_in[11];
    const float* Wh2  = (const float*)d_in[12];
    const float* bh2  = (const float*)d_in[13];
    const float* Wh3  = (const float*)d_in[14];
    const float* bh3  = (const float*)d_in[15];
    const float* Wh4  = (const float*)d_in[16];
    const float* bh4  = (const float*)d_in[17];
    float* out = (float*)d_out;

    char* ws = (char*)d_ws;
    double* stats = (double*)ws;                       // 3 layers x B x {sum,sumsq}
    const size_t statsBytes = 3 * B_ * 2 * sizeof(double);

    // region A = max(t0, t2) = t2 bytes; region B = max(t1, t3) = t1 bytes
    const size_t offA = 8192;
    const size_t offB = offA + (size_t)B_ * MM_ * C2_ * sizeof(float); // 134,348,800
    float* t0 = (float*)(ws + offA);
    float* t1 = (float*)(ws + offB);
    float* t2 = (float*)(ws + offA);
    float* t3 = (float*)(ws + offB);

    hipMemsetAsync(stats, 0, statsBytes, stream);

    const dim3 blk(256);
    enc_kernel<<<dim3(17, 2, B_), blk, 0, stream>>>(x, Wenc, benc, t0);

    conv_kernel<CH0_, C1_, false><<<dim3(8, 4, B_), blk, 0, stream>>>(
        t0, idx, W1, b1, nullptr, 1, stats + 0, t1);

    conv_kernel<C1_, C2_, true><<<dim3(8, 2, B_), blk, 0, stream>>>(
        t1, idx, W2, b2, stats + 0, C1_ * MM_, stats + 2 * B_, t2);

    conv_kernel<C2_, C3_, true><<<dim3(8, 1, B_), blk, 0, stream>>>(
        t2, idx, W3, b3, stats + 2 * B_, C2_ * MM_, stats + 4 * B_, t3);

    pool_head_kernel<<<dim3(B_), dim3(128), 0, stream>>>(
        t3, stats + 4 * B_, Wh1, bh1, Wh2, bh2, Wh3, bh3, Wh4, bh4, out);
}

// Round 2
// 1274.585 us; speedup vs baseline: 2.1076x; 2.1076x over previous
//
#include <hip/hip_runtime.h>
#include <hip/hip_bf16.h>
#include <math.h>

#define B_   128
#define FQ_  318
#define CH0_ 109
#define NN_  1024
#define MM_  1025
#define C1_  512
#define C2_  256
#define C3_  128

typedef _Float16 f16x8 __attribute__((ext_vector_type(8)));
typedef float    f32x4 __attribute__((ext_vector_type(4)));

// ---------------------------------------------------------------------------
// Encoder: t0[b, m, c] = sum_f x[b, f, m] * Wenc[c, f] + benc[c];  row m==0 -> 0
// t0 layout: (B, 1025, 109) node-major so the next layer's gather is coalesced.
// ---------------------------------------------------------------------------
__global__ __launch_bounds__(256) void enc_kernel(
    const float* __restrict__ x, const float* __restrict__ Wenc,
    const float* __restrict__ benc, float* __restrict__ t0)
{
    __shared__ __align__(16) float Xs[16][68];   // [f_local][m_local]
    __shared__ __align__(16) float WsT[16][68];  // [f_local][c_local]

    const int tid = threadIdx.x;
    const int b  = blockIdx.z;
    const int m0 = blockIdx.x * 64;
    const int c0 = blockIdx.y * 64;
    const int txc = tid & 15;
    const int tym = tid >> 4;

    float acc[4][4];
#pragma unroll
    for (int i = 0; i < 4; ++i)
#pragma unroll
        for (int j = 0; j < 4; ++j) acc[i][j] = 0.f;

    const int ml = tid & 63;
    const int kq = tid >> 6;
    const int wl = tid & 15;
    const int wg = tid >> 4;

    for (int f0 = 0; f0 < FQ_; f0 += 16) {
#pragma unroll
        for (int i = 0; i < 4; ++i) {
            const int k = kq * 4 + i;
            const int f = f0 + k;
            const int m = m0 + ml;
            Xs[k][ml] = (f < FQ_ && m < MM_)
                        ? x[(size_t)b * FQ_ * MM_ + (size_t)f * MM_ + m] : 0.f;
        }
#pragma unroll
        for (int pass = 0; pass < 4; ++pass) {
            const int cl = pass * 16 + wg;
            const int f  = f0 + wl;
            WsT[wl][cl] = (c0 + cl < CH0_ && f < FQ_)
                          ? Wenc[(size_t)(c0 + cl) * FQ_ + f] : 0.f;
        }
        __syncthreads();
#pragma unroll
        for (int k = 0; k < 16; ++k) {
            const float4 a = *reinterpret_cast<const float4*>(&Xs[k][tym * 4]);
            const float4 w = *reinterpret_cast<const float4*>(&WsT[k][txc * 4]);
            const float av[4] = {a.x, a.y, a.z, a.w};
            const float wv[4] = {w.x, w.y, w.z, w.w};
#pragma unroll
            for (int i = 0; i < 4; ++i)
#pragma unroll
                for (int j = 0; j < 4; ++j)
                    acc[i][j] = fmaf(av[i], wv[j], acc[i][j]);
        }
        __syncthreads();
    }

#pragma unroll
    for (int i = 0; i < 4; ++i) {
        const int m = m0 + tym * 4 + i;
        if (m >= MM_) continue;
#pragma unroll
        for (int j = 0; j < 4; ++j) {
            const int c = c0 + txc * 4 + j;
            if (c >= CH0_) continue;
            const float v = (m == 0) ? 0.f : (acc[i][j] + benc[c]);
            t0[((size_t)b * MM_ + m) * CH0_ + c] = v;
        }
    }
}

// ---------------------------------------------------------------------------
// Weight prep: reorder W (C_OUT, C_IN, 3) -> k-major Wr[o][kk*C_IN_PAD + c],
// split fp32 into f16 hi + f16 lo. Pad region (c >= C_IN) is zero.
// ---------------------------------------------------------------------------
template <int C_IN, int C_IN_PAD, int C_OUT>
__global__ __launch_bounds__(256) void wprep_kernel(
    const float* __restrict__ W, _Float16* __restrict__ Wh, _Float16* __restrict__ Wl)
{
    constexpr int KP = 3 * C_IN_PAD;
    const int id = blockIdx.x * 256 + threadIdx.x;
    if (id >= C_OUT * KP) return;
    const int o = id / KP, k = id - o * KP;
    const int kk = k / C_IN_PAD, c = k - kk * C_IN_PAD;
    const float v = (c < C_IN) ? W[((size_t)o * C_IN + c) * 3 + kk] : 0.f;
    const _Float16 h = (_Float16)v;
    Wh[id] = h;
    Wl[id] = (_Float16)(v - (float)h);
}

// ---------------------------------------------------------------------------
// MFMA gather-conv layer, split-f16 3-term (hi*hi + hi*lo + lo*hi).
// Block: 512 threads (8 waves), tile 256 nodes x 128 out-channels.
// Wave (wr 0..3, wc 0..1): 64x64 sub-tile = 4x4 frags of 16x16, K=32/chunk.
// LDS rows: 40 f16 = 80 B stride -> uniform bank slots for b128 r/w.
// out[b, n+1, o] = bias[o] + sum_k normIn(gather) * W ; out[b,0,:] = 0.
// Stats (sum, sumsq) of raw output accumulated for next layer's TreeLayerNorm.
// ---------------------------------------------------------------------------
template <int C_IN, int C_IN_PAD, int C_OUT, bool NORM>
__global__ __launch_bounds__(512) void conv_mfma_kernel(
    const float* __restrict__ tin, const int* __restrict__ idx,
    const _Float16* __restrict__ Wh, const _Float16* __restrict__ Wl,
    const float* __restrict__ bias,
    const double* __restrict__ stats_in, const int prev_count,
    double* __restrict__ stats_out, float* __restrict__ tout)
{
    constexpr int KP  = 3 * C_IN_PAD;
    constexpr int NC  = KP / 32;          // k-chunks
    constexpr int CPC = C_IN_PAD / 32;    // chunks per child (power of 2)
    constexpr int OT  = C_OUT / 128;
    static_assert(KP % 32 == 0 && (CPC & (CPC - 1)) == 0, "bad pad");

    __shared__ __align__(16) _Float16 GhS[256 * 40];
    __shared__ __align__(16) _Float16 GlS[256 * 40];
    __shared__ __align__(16) _Float16 WhS[128 * 40];
    __shared__ __align__(16) _Float16 WlS[128 * 40];
    __shared__ int idxs[768];
    __shared__ float s_norm[2];
    __shared__ double redS[8], redQ[8];

    const int tid = threadIdx.x;

    // XCD-aware bijective swizzle (nwg % 8 == 0 for all instantiations)
    const int nwg  = 4 * OT * B_;
    const int cpx  = nwg >> 3;
    const int orig = blockIdx.x;
    const int swz  = (orig & 7) * cpx + (orig >> 3);
    const int b    = swz / (4 * OT);
    const int rr   = swz - b * (4 * OT);
    const int mt   = rr / OT;
    const int ot   = rr - mt * OT;
    const int n_base = mt * 256;
    const int o0     = ot * 128;

    {   // idx triples for this block's 256 nodes
        const int* ip = idx + (size_t)b * (3 * NN_) + n_base * 3;
        idxs[tid] = ip[tid];
        if (tid < 256) idxs[512 + tid] = ip[512 + tid];
    }
    if (NORM && tid == 0) {
        const double s = stats_in[2 * b], q = stats_in[2 * b + 1];
        const double meand = s / prev_count;
        const double var   = (q - s * s / prev_count) / (prev_count - 1);
        s_norm[0] = (float)meand;
        s_norm[1] = (float)(1.0 / (sqrt(var) + 1e-5));
    }
    __syncthreads();
    const float mean = NORM ? s_norm[0] : 0.f;
    const float inv  = NORM ? s_norm[1] : 0.f;

    // staging roles
    const float* tb = tin + (size_t)b * MM_ * C_IN;
    const int gn = tid >> 1, gh = tid & 1;    // gather: 256 n x 2 halves of 16
    const int wo = tid >> 2, wq = tid & 3;    // W: 128 o x 4 quads of 8

    float gv[16];
    uint4 wvh, wvl;

    auto load_chunk = [&](int ch) {
        const int kk = ch / CPC;
        const int c0 = (ch & (CPC - 1)) * 32;
        const int r  = idxs[gn * 3 + kk];
        const float* src = tb + (size_t)r * C_IN + c0 + gh * 16;
        if constexpr (C_IN == C_IN_PAD) {
#pragma unroll
            for (int q = 0; q < 4; ++q) {
                const float4 v = *reinterpret_cast<const float4*>(src + q * 4);
                gv[q * 4 + 0] = v.x; gv[q * 4 + 1] = v.y;
                gv[q * 4 + 2] = v.z; gv[q * 4 + 3] = v.w;
            }
        } else {
#pragma unroll
            for (int e = 0; e < 16; ++e) {
                const int c = c0 + gh * 16 + e;
                gv[e] = (c < C_IN) ? src[e] : 0.f;
            }
        }
        const size_t wbase = (size_t)(o0 + wo) * KP + ch * 32 + wq * 8;
        wvh = *reinterpret_cast<const uint4*>(Wh + wbase);
        wvl = *reinterpret_cast<const uint4*>(Wl + wbase);
    };

    auto store_chunk = [&]() {
        _Float16 hh[16], ll[16];
#pragma unroll
        for (int e = 0; e < 16; ++e) {
            float v = gv[e];
            if (NORM) v = fmaxf(0.f, (v - mean) * inv);
            const _Float16 h = (_Float16)v;
            hh[e] = h;
            ll[e] = (_Float16)(v - (float)h);
        }
        _Float16* gdh = &GhS[gn * 40 + gh * 16];
        _Float16* gdl = &GlS[gn * 40 + gh * 16];
#pragma unroll
        for (int hf = 0; hf < 2; ++hf) {
            f16x8 vh, vl;
#pragma unroll
            for (int e = 0; e < 8; ++e) { vh[e] = hh[hf * 8 + e]; vl[e] = ll[hf * 8 + e]; }
            *reinterpret_cast<f16x8*>(gdh + hf * 8) = vh;
            *reinterpret_cast<f16x8*>(gdl + hf * 8) = vl;
        }
        *reinterpret_cast<uint4*>(&WhS[wo * 40 + wq * 8]) = wvh;
        *reinterpret_cast<uint4*>(&WlS[wo * 40 + wq * 8]) = wvl;
    };

    // compute roles
    const int lane = tid & 63, wid = tid >> 6;
    const int wr = wid >> 1, wc = wid & 1;
    const int lrow = lane & 15, lkg = lane >> 4;

    f32x4 acc[4][4];
#pragma unroll
    for (int i = 0; i < 4; ++i)
#pragma unroll
        for (int j = 0; j < 4; ++j) acc[i][j] = (f32x4){0.f, 0.f, 0.f, 0.f};

    auto compute_chunk = [&]() {
        f16x8 ah[4], al[4], bh[4], bl[4];
#pragma unroll
        for (int f = 0; f < 4; ++f) {
            const int ar = wr * 64 + f * 16 + lrow;
            ah[f] = *reinterpret_cast<const f16x8*>(&GhS[ar * 40 + lkg * 8]);
            al[f] = *reinterpret_cast<const f16x8*>(&GlS[ar * 40 + lkg * 8]);
            const int br = wc * 64 + f * 16 + lrow;
            bh[f] = *reinterpret_cast<const f16x8*>(&WhS[br * 40 + lkg * 8]);
            bl[f] = *reinterpret_cast<const f16x8*>(&WlS[br * 40 + lkg * 8]);
        }
#pragma unroll
        for (int i = 0; i < 4; ++i)
#pragma unroll
            for (int j = 0; j < 4; ++j) {
                acc[i][j] = __builtin_amdgcn_mfma_f32_16x16x32_f16(ah[i], bh[j], acc[i][j], 0, 0, 0);
                acc[i][j] = __builtin_amdgcn_mfma_f32_16x16x32_f16(ah[i], bl[j], acc[i][j], 0, 0, 0);
                acc[i][j] = __builtin_amdgcn_mfma_f32_16x16x32_f16(al[i], bh[j], acc[i][j], 0, 0, 0);
            }
    };

    // pipeline: issue loads early, write LDS late (T14)
    load_chunk(0);
    store_chunk();
    __syncthreads();
    for (int ch = 0; ch < NC; ++ch) {
        if (ch + 1 < NC) load_chunk(ch + 1);
        compute_chunk();
        __syncthreads();
        if (ch + 1 < NC) {
            store_chunk();
            __syncthreads();
        }
    }

    // epilogue: bias, store raw fp32, stats
    double s = 0.0, q = 0.0;
    float* outb = tout + (size_t)b * MM_ * C_OUT;
#pragma unroll
    for (int i = 0; i < 4; ++i) {
        const int nrow = n_base + wr * 64 + i * 16 + lkg * 4;
#pragma unroll
        for (int j = 0; j < 4; ++j) {
            const int o = o0 + wc * 64 + j * 16 + lrow;
            const float bb = bias[o];
#pragma unroll
            for (int r = 0; r < 4; ++r) {
                const float v = acc[i][j][r] + bb;
                outb[(size_t)(nrow + r + 1) * C_OUT + o] = v;
                s += (double)v;
                q += (double)v * (double)v;
            }
        }
    }
    if (mt == 0 && ot == 0 && tid < C_OUT) outb[tid] = 0.f;   // null slot row
    if (mt == 0 && OT > 1 && ot > 0 && tid < 128) outb[o0 + tid] = 0.f;

#pragma unroll
    for (int off = 32; off > 0; off >>= 1) {
        s += __shfl_down(s, off);
        q += __shfl_down(q, off);
    }
    if (lane == 0) { redS[wid] = s; redQ[wid] = q; }
    __syncthreads();
    if (tid == 0) {
        double ts = 0.0, tq = 0.0;
#pragma unroll
        for (int w = 0; w < 8; ++w) { ts += redS[w]; tq += redQ[w]; }
        atomicAdd(&stats_out[2 * b], ts);
        atomicAdd(&stats_out[2 * b + 1], tq);
    }
}

// ---------------------------------------------------------------------------
// Fused: normalize t3 on the fly, max-pool over 1025 nodes, then the MLP head.
// ---------------------------------------------------------------------------
__global__ __launch_bounds__(128) void pool_head_kernel(
    const float* __restrict__ t3, const double* __restrict__ stats3,
    const float* __restrict__ Wh1, const float* __restrict__ bh1,
    const float* __restrict__ Wh2, const float* __restrict__ bh2,
    const float* __restrict__ Wh3, const float* __restrict__ bh3,
    const float* __restrict__ Wh4, const float* __restrict__ bh4,
    float* __restrict__ out)
{
    __shared__ float hs[128], h1s[128], h2s[64], h3s[32];
    const int b = blockIdx.x, o = threadIdx.x;

    const double ssum = stats3[2 * b], ssq = stats3[2 * b + 1];
    const double cnt  = (double)C3_ * (double)MM_;
    const double meand = ssum / cnt;
    const double var   = (ssq - ssum * ssum / cnt) / (cnt - 1.0);
    const float mean = (float)meand;
    const float inv  = (float)(1.0 / (sqrt(var) + 1e-5));

    const float* tb = t3 + (size_t)b * MM_ * C3_;
    float best = 0.f;
    for (int m = 0; m < MM_; ++m) {
        const float v = fmaxf(0.f, (tb[(size_t)m * C3_ + o] - mean) * inv);
        best = fmaxf(best, v);
    }
    hs[o] = best;
    __syncthreads();

    float a1 = bh1[o];
    for (int i = 0; i < 128; ++i) a1 = fmaf(Wh1[o * 128 + i], hs[i], a1);
    h1s[o] = fmaxf(a1, 0.f);
    __syncthreads();

    if (o < 64) {
        float a2 = bh2[o];
        for (int i = 0; i < 128; ++i) a2 = fmaf(Wh2[o * 128 + i], h1s[i], a2);
        h2s[o] = fmaxf(a2, 0.f);
    }
    __syncthreads();

    if (o < 32) {
        float a3 = bh3[o];
        for (int i = 0; i < 64; ++i) a3 = fmaf(Wh3[o * 64 + i], h2s[i], a3);
        h3s[o] = fmaxf(a3, 0.f);
    }
    __syncthreads();

    if (o == 0) {
        float a4 = bh4[0];
        for (int i = 0; i < 32; ++i) a4 = fmaf(Wh4[i], h3s[i], a4);
        out[b] = a4;
    }
}

// ---------------------------------------------------------------------------
extern "C" void kernel_launch(void* const* d_in, const int* in_sizes, int n_in,
                              void* d_out, int out_size, void* d_ws, size_t ws_size,
                              hipStream_t stream)
{
    const float* x    = (const float*)d_in[0];
    const int*   idx  = (const int*)d_in[1];
    const float* Wenc = (const float*)d_in[2];
    const float* benc = (const float*)d_in[3];
    const float* W1   = (const float*)d_in[4];
    const float* b1   = (const float*)d_in[5];
    const float* W2   = (const float*)d_in[6];
    const float* b2   = (const float*)d_in[7];
    const float* W3   = (const float*)d_in[8];
    const float* b3   = (const float*)d_in[9];
    const float* Wh1  = (const float*)d_in[10];
    const float* bh1  = (const float*)d_in[11];
    const float* Wh2  = (const float*)d_in[12];
    const float* bh2  = (const float*)d_in[13];
    const float* Wh3  = (const float*)d_in[14];
    const float* bh3  = (const float*)d_in[15];
    const float* Wh4  = (const float*)d_in[16];
    const float* bh4  = (const float*)d_in[17];
    float* out = (float*)d_out;

    char* ws = (char*)d_ws;
    // workspace layout (bytes)
    double* stats = (double*)ws;                          // 3 x B x {sum,sumsq} = 6144 B
    _Float16* w1h = (_Float16*)(ws + 8192);               // 512*384*2   = 393216
    _Float16* w1l = (_Float16*)(ws + 401408);
    _Float16* w2h = (_Float16*)(ws + 794624);             // 256*1536*2  = 786432
    _Float16* w2l = (_Float16*)(ws + 1581056);
    _Float16* w3h = (_Float16*)(ws + 2367488);            // 128*768*2   = 196608
    _Float16* w3l = (_Float16*)(ws + 2564096);
    const size_t offA = 2762752;                          // t0 / t2 region
    const size_t offB = offA + (size_t)B_ * MM_ * C2_ * sizeof(float);  // t1 / t3
    float* t0 = (float*)(ws + offA);
    float* t1 = (float*)(ws + offB);
    float* t2 = (float*)(ws + offA);
    float* t3 = (float*)(ws + offB);

    hipMemsetAsync(stats, 0, 3 * B_ * 2 * sizeof(double), stream);

    wprep_kernel<CH0_, 128, C1_><<<dim3((C1_ * 384 + 255) / 256), dim3(256), 0, stream>>>(W1, w1h, w1l);
    wprep_kernel<C1_,  C1_, C2_><<<dim3((C2_ * 1536 + 255) / 256), dim3(256), 0, stream>>>(W2, w2h, w2l);
    wprep_kernel<C2_,  C2_, C3_><<<dim3((C3_ * 768 + 255) / 256), dim3(256), 0, stream>>>(W3, w3h, w3l);

    enc_kernel<<<dim3(17, 2, B_), dim3(256), 0, stream>>>(x, Wenc, benc, t0);

    conv_mfma_kernel<CH0_, 128, C1_, false><<<dim3(4 * 4 * B_), dim3(512), 0, stream>>>(
        t0, idx, w1h, w1l, b1, nullptr, 1, stats + 0, t1);

    conv_mfma_kernel<C1_, C1_, C2_, true><<<dim3(4 * 2 * B_), dim3(512), 0, stream>>>(
        t1, idx, w2h, w2l, b2, stats + 0, C1_ * MM_, stats + 2 * B_, t2);

    conv_mfma_kernel<C2_, C2_, C3_, true><<<dim3(4 * 1 * B_), dim3(512), 0, stream>>>(
        t2, idx, w3h, w3l, b3, stats + 2 * B_, C2_ * MM_, stats + 4 * B_, t3);

    pool_head_kernel<<<dim3(B_), dim3(128), 0, stream>>>(
        t3, stats + 4 * B_, Wh1, bh1, Wh2, bh2, Wh3, bh3, Wh4, bh4, out);
}

// Round 3
// 964.438 us; speedup vs baseline: 2.7854x; 1.3216x over previous
//
#include <hip/hip_runtime.h>
#include <hip/hip_bf16.h>
#include <math.h>

#define B_   128
#define FQ_  318
#define CH0_ 109
#define NN_  1024
#define MM_  1025
#define C1_  512
#define C2_  256
#define C3_  128
#define C0P_ 128   // t0 channel padding (109 -> 128)

typedef _Float16 f16x8 __attribute__((ext_vector_type(8)));
typedef float    f32x4 __attribute__((ext_vector_type(4)));

// ---------------------------------------------------------------------------
// Encoder: t0[b, m, c] = sum_f x[b, f, m] * Wenc[c, f] + benc[c]
// t0 layout: (B, 1025, 128) node-major, channels padded 109->128 with zeros,
// row m==0 zeroed. Pad lets conv1 use unguarded float4 gathers.
// ---------------------------------------------------------------------------
__global__ __launch_bounds__(256) void enc_kernel(
    const float* __restrict__ x, const float* __restrict__ Wenc,
    const float* __restrict__ benc, float* __restrict__ t0)
{
    __shared__ __align__(16) float Xs[16][68];   // [f_local][m_local]
    __shared__ __align__(16) float WsT[16][68];  // [f_local][c_local]

    const int tid = threadIdx.x;
    const int b  = blockIdx.z;
    const int m0 = blockIdx.x * 64;
    const int c0 = blockIdx.y * 64;
    const int txc = tid & 15;
    const int tym = tid >> 4;

    float acc[4][4];
#pragma unroll
    for (int i = 0; i < 4; ++i)
#pragma unroll
        for (int j = 0; j < 4; ++j) acc[i][j] = 0.f;

    const int ml = tid & 63;
    const int kq = tid >> 6;
    const int wl = tid & 15;
    const int wg = tid >> 4;

    for (int f0 = 0; f0 < FQ_; f0 += 16) {
#pragma unroll
        for (int i = 0; i < 4; ++i) {
            const int k = kq * 4 + i;
            const int f = f0 + k;
            const int m = m0 + ml;
            Xs[k][ml] = (f < FQ_ && m < MM_)
                        ? x[(size_t)b * FQ_ * MM_ + (size_t)f * MM_ + m] : 0.f;
        }
#pragma unroll
        for (int pass = 0; pass < 4; ++pass) {
            const int cl = pass * 16 + wg;
            const int f  = f0 + wl;
            WsT[wl][cl] = (c0 + cl < CH0_ && f < FQ_)
                          ? Wenc[(size_t)(c0 + cl) * FQ_ + f] : 0.f;
        }
        __syncthreads();
#pragma unroll
        for (int k = 0; k < 16; ++k) {
            const float4 a = *reinterpret_cast<const float4*>(&Xs[k][tym * 4]);
            const float4 w = *reinterpret_cast<const float4*>(&WsT[k][txc * 4]);
            const float av[4] = {a.x, a.y, a.z, a.w};
            const float wv[4] = {w.x, w.y, w.z, w.w};
#pragma unroll
            for (int i = 0; i < 4; ++i)
#pragma unroll
                for (int j = 0; j < 4; ++j)
                    acc[i][j] = fmaf(av[i], wv[j], acc[i][j]);
        }
        __syncthreads();
    }

#pragma unroll
    for (int i = 0; i < 4; ++i) {
        const int m = m0 + tym * 4 + i;
        if (m >= MM_) continue;
#pragma unroll
        for (int j = 0; j < 4; ++j) {
            const int c = c0 + txc * 4 + j;           // always < 128
            const bool valid = (m != 0) && (c < CH0_);
            const float v = valid ? (acc[i][j] + benc[c < CH0_ ? c : 0]) : 0.f;
            t0[((size_t)b * MM_ + m) * C0P_ + c] = v;
        }
    }
}

// ---------------------------------------------------------------------------
// Weight prep: reorder W (C_OUT, C_IN, 3) -> k-major Wr[o][kk*C_IN_PAD + c],
// split fp32 into f16 hi + f16 lo. Pad region (c >= C_IN) is zero.
// ---------------------------------------------------------------------------
template <int C_IN, int C_IN_PAD, int C_OUT>
__global__ __launch_bounds__(256) void wprep_kernel(
    const float* __restrict__ W, _Float16* __restrict__ Wh, _Float16* __restrict__ Wl)
{
    constexpr int KP = 3 * C_IN_PAD;
    const int id = blockIdx.x * 256 + threadIdx.x;
    if (id >= C_OUT * KP) return;
    const int o = id / KP, k = id - o * KP;
    const int kk = k / C_IN_PAD, c = k - kk * C_IN_PAD;
    const float v = (c < C_IN) ? W[((size_t)o * C_IN + c) * 3 + kk] : 0.f;
    const _Float16 h = (_Float16)v;
    Wh[id] = h;
    Wl[id] = (_Float16)(v - (float)h);
}

// ---------------------------------------------------------------------------
// MFMA gather-conv, split-f16 3-term, double-buffered LDS, ONE barrier/chunk.
// Block: 512 threads (8 waves), tile 256 nodes x 128 out-channels.
// Wave (wr 0..3, wc 0..1): 64x64 sub-tile = 4x4 frags of 16x16x32.
// C_IN_STRIDE is the stored row stride of tin (conv1: 128-padded).
// out[b, n+1, o] = inv_in * conv(relu(gather - mean_in)) + bias ; out[b,0,:]=0.
// ---------------------------------------------------------------------------
template <int C_IN_STRIDE, int C_OUT, bool NORM>
__global__ __launch_bounds__(512, 2) void conv_mfma_kernel(
    const float* __restrict__ tin, const int* __restrict__ idx,
    const _Float16* __restrict__ Wh, const _Float16* __restrict__ Wl,
    const float* __restrict__ bias,
    const double* __restrict__ stats_in, const int prev_count,
    double* __restrict__ stats_out, float* __restrict__ tout)
{
    constexpr int KP  = 3 * C_IN_STRIDE;
    constexpr int NC  = KP / 32;               // k-chunks
    constexpr int CPC = C_IN_STRIDE / 32;      // chunks per child (power of 2)
    constexpr int OT  = C_OUT / 128;
    static_assert(KP % 32 == 0 && (CPC & (CPC - 1)) == 0, "bad pad");

    __shared__ __align__(16) _Float16 GhS[2][256 * 40];
    __shared__ __align__(16) _Float16 GlS[2][256 * 40];
    __shared__ __align__(16) _Float16 WhS[2][128 * 40];
    __shared__ __align__(16) _Float16 WlS[2][128 * 40];
    __shared__ int idxs[768];
    __shared__ float s_norm[2];
    __shared__ double redS[8], redQ[8];

    const int tid = threadIdx.x;

    // XCD-aware bijective swizzle (nwg % 8 == 0 for all instantiations)
    const int nwg  = 4 * OT * B_;
    const int cpx  = nwg >> 3;
    const int orig = blockIdx.x;
    const int swz  = (orig & 7) * cpx + (orig >> 3);
    const int b    = swz / (4 * OT);
    const int rr   = swz - b * (4 * OT);
    const int mt   = rr / OT;
    const int ot   = rr - mt * OT;
    const int n_base = mt * 256;
    const int o0     = ot * 128;

    {   // idx triples for this block's 256 nodes
        const int* ip = idx + (size_t)b * (3 * NN_) + n_base * 3;
        idxs[tid] = ip[tid];
        if (tid < 256) idxs[512 + tid] = ip[512 + tid];
    }
    if (NORM && tid == 0) {
        const double s = stats_in[2 * b], q = stats_in[2 * b + 1];
        const double meand = s / prev_count;
        const double var   = (q - s * s / prev_count) / (prev_count - 1);
        s_norm[0] = (float)meand;
        s_norm[1] = (float)(1.0 / (sqrt(var) + 1e-5));
    }
    __syncthreads();
    const float mean = NORM ? s_norm[0] : 0.f;
    const float inv  = NORM ? s_norm[1] : 1.f;

    // staging roles
    const float* tb = tin + (size_t)b * MM_ * C_IN_STRIDE;
    const int gn = tid >> 1, gh = tid & 1;    // gather: 256 n x 2 halves of 16
    const int wo = tid >> 2, wq = tid & 3;    // W: 128 o x 4 quads of 8

    float4 gv[4];
    uint4 wvh, wvl;

    auto load_chunk = [&](int ch) {
        const int kk = ch / CPC;
        const int c0 = (ch & (CPC - 1)) * 32;
        const int r  = idxs[gn * 3 + kk];
        const float* src = tb + (size_t)r * C_IN_STRIDE + c0 + gh * 16;
#pragma unroll
        for (int q = 0; q < 4; ++q)
            gv[q] = *reinterpret_cast<const float4*>(src + q * 4);
        const size_t wbase = (size_t)(o0 + wo) * KP + ch * 32 + wq * 8;
        wvh = *reinterpret_cast<const uint4*>(Wh + wbase);
        wvl = *reinterpret_cast<const uint4*>(Wl + wbase);
    };

    auto store_chunk = [&](int buf) {
        float vv[16];
#pragma unroll
        for (int q = 0; q < 4; ++q) {
            vv[q * 4 + 0] = gv[q].x; vv[q * 4 + 1] = gv[q].y;
            vv[q * 4 + 2] = gv[q].z; vv[q * 4 + 3] = gv[q].w;
        }
        _Float16 hh[16], ll[16];
#pragma unroll
        for (int e = 0; e < 16; ++e) {
            float v = vv[e];
            if (NORM) v = fmaxf(0.f, v - mean);   // inv folded into epilogue
            const _Float16 h = (_Float16)v;
            hh[e] = h;
            ll[e] = (_Float16)(v - (float)h);
        }
        _Float16* gdh = &GhS[buf][gn * 40 + gh * 16];
        _Float16* gdl = &GlS[buf][gn * 40 + gh * 16];
#pragma unroll
        for (int hf = 0; hf < 2; ++hf) {
            f16x8 vh, vl;
#pragma unroll
            for (int e = 0; e < 8; ++e) { vh[e] = hh[hf * 8 + e]; vl[e] = ll[hf * 8 + e]; }
            *reinterpret_cast<f16x8*>(gdh + hf * 8) = vh;
            *reinterpret_cast<f16x8*>(gdl + hf * 8) = vl;
        }
        *reinterpret_cast<uint4*>(&WhS[buf][wo * 40 + wq * 8]) = wvh;
        *reinterpret_cast<uint4*>(&WlS[buf][wo * 40 + wq * 8]) = wvl;
    };

    // compute roles
    const int lane = tid & 63, wid = tid >> 6;
    const int wr = wid >> 1, wc = wid & 1;
    const int lrow = lane & 15, lkg = lane >> 4;

    f32x4 acc[4][4];
#pragma unroll
    for (int i = 0; i < 4; ++i)
#pragma unroll
        for (int j = 0; j < 4; ++j) acc[i][j] = (f32x4){0.f, 0.f, 0.f, 0.f};

    auto compute_chunk = [&](int buf) {
        f16x8 ah[4], al[4], bh[4], bl[4];
#pragma unroll
        for (int f = 0; f < 4; ++f) {
            const int ar = wr * 64 + f * 16 + lrow;
            ah[f] = *reinterpret_cast<const f16x8*>(&GhS[buf][ar * 40 + lkg * 8]);
            al[f] = *reinterpret_cast<const f16x8*>(&GlS[buf][ar * 40 + lkg * 8]);
            const int br = wc * 64 + f * 16 + lrow;
            bh[f] = *reinterpret_cast<const f16x8*>(&WhS[buf][br * 40 + lkg * 8]);
            bl[f] = *reinterpret_cast<const f16x8*>(&WlS[buf][br * 40 + lkg * 8]);
        }
        __builtin_amdgcn_s_setprio(1);
#pragma unroll
        for (int i = 0; i < 4; ++i)
#pragma unroll
            for (int j = 0; j < 4; ++j)
                acc[i][j] = __builtin_amdgcn_mfma_f32_16x16x32_f16(ah[i], bh[j], acc[i][j], 0, 0, 0);
#pragma unroll
        for (int i = 0; i < 4; ++i)
#pragma unroll
            for (int j = 0; j < 4; ++j)
                acc[i][j] = __builtin_amdgcn_mfma_f32_16x16x32_f16(ah[i], bl[j], acc[i][j], 0, 0, 0);
#pragma unroll
        for (int i = 0; i < 4; ++i)
#pragma unroll
            for (int j = 0; j < 4; ++j)
                acc[i][j] = __builtin_amdgcn_mfma_f32_16x16x32_f16(al[i], bh[j], acc[i][j], 0, 0, 0);
        __builtin_amdgcn_s_setprio(0);
    };

    // pipeline: dbuf LDS, one barrier per chunk
    load_chunk(0);
    store_chunk(0);
    __syncthreads();
    for (int ch = 0; ch < NC; ++ch) {
        if (ch + 1 < NC) load_chunk(ch + 1);   // global -> regs (latency under MFMA)
        compute_chunk(ch & 1);
        if (ch + 1 < NC) store_chunk((ch + 1) & 1);  // other buffer: no hazard
        __syncthreads();
    }

    // epilogue: scale by inv, add bias, store raw fp32, stats
    const float scale = inv;
    double s = 0.0, q = 0.0;
    float* outb = tout + (size_t)b * MM_ * C_OUT;
#pragma unroll
    for (int i = 0; i < 4; ++i) {
        const int nrow = n_base + wr * 64 + i * 16 + lkg * 4;
#pragma unroll
        for (int j = 0; j < 4; ++j) {
            const int o = o0 + wc * 64 + j * 16 + lrow;
            const float bb = bias[o];
#pragma unroll
            for (int r = 0; r < 4; ++r) {
                const float v = fmaf(acc[i][j][r], scale, bb);
                outb[(size_t)(nrow + r + 1) * C_OUT + o] = v;
                s += (double)v;
                q += (double)v * (double)v;
            }
        }
    }
    if (mt == 0 && ot == 0 && tid < C_OUT) outb[tid] = 0.f;   // null slot row
    if (mt == 0 && OT > 1 && ot > 0 && tid < 128) outb[o0 + tid] = 0.f;

#pragma unroll
    for (int off = 32; off > 0; off >>= 1) {
        s += __shfl_down(s, off);
        q += __shfl_down(q, off);
    }
    if (lane == 0) { redS[wid] = s; redQ[wid] = q; }
    __syncthreads();
    if (tid == 0) {
        double ts = 0.0, tq = 0.0;
#pragma unroll
        for (int w = 0; w < 8; ++w) { ts += redS[w]; tq += redQ[w]; }
        atomicAdd(&stats_out[2 * b], ts);
        atomicAdd(&stats_out[2 * b + 1], tq);
    }
}

// ---------------------------------------------------------------------------
// Fused: normalize t3 on the fly, max-pool over 1025 nodes, then the MLP head.
// ---------------------------------------------------------------------------
__global__ __launch_bounds__(128) void pool_head_kernel(
    const float* __restrict__ t3, const double* __restrict__ stats3,
    const float* __restrict__ Wh1, const float* __restrict__ bh1,
    const float* __restrict__ Wh2, const float* __restrict__ bh2,
    const float* __restrict__ Wh3, const float* __restrict__ bh3,
    const float* __restrict__ Wh4, const float* __restrict__ bh4,
    float* __restrict__ out)
{
    __shared__ float hs[128], h1s[128], h2s[64], h3s[32];
    const int b = blockIdx.x, o = threadIdx.x;

    const double ssum = stats3[2 * b], ssq = stats3[2 * b + 1];
    const double cnt  = (double)C3_ * (double)MM_;
    const double meand = ssum / cnt;
    const double var   = (ssq - ssum * ssum / cnt) / (cnt - 1.0);
    const float mean = (float)meand;
    const float inv  = (float)(1.0 / (sqrt(var) + 1e-5));

    const float* tb = t3 + (size_t)b * MM_ * C3_;
    float best = 0.f;
    for (int m = 0; m < MM_; ++m) {
        const float v = fmaxf(0.f, (tb[(size_t)m * C3_ + o] - mean) * inv);
        best = fmaxf(best, v);
    }
    hs[o] = best;
    __syncthreads();

    float a1 = bh1[o];
    for (int i = 0; i < 128; ++i) a1 = fmaf(Wh1[o * 128 + i], hs[i], a1);
    h1s[o] = fmaxf(a1, 0.f);
    __syncthreads();

    if (o < 64) {
        float a2 = bh2[o];
        for (int i = 0; i < 128; ++i) a2 = fmaf(Wh2[o * 128 + i], h1s[i], a2);
        h2s[o] = fmaxf(a2, 0.f);
    }
    __syncthreads();

    if (o < 32) {
        float a3 = bh3[o];
        for (int i = 0; i < 64; ++i) a3 = fmaf(Wh3[o * 64 + i], h2s[i], a3);
        h3s[o] = fmaxf(a3, 0.f);
    }
    __syncthreads();

    if (o == 0) {
        float a4 = bh4[0];
        for (int i = 0; i < 32; ++i) a4 = fmaf(Wh4[i], h3s[i], a4);
        out[b] = a4;
    }
}

// ---------------------------------------------------------------------------
extern "C" void kernel_launch(void* const* d_in, const int* in_sizes, int n_in,
                              void* d_out, int out_size, void* d_ws, size_t ws_size,
                              hipStream_t stream)
{
    const float* x    = (const float*)d_in[0];
    const int*   idx  = (const int*)d_in[1];
    const float* Wenc = (const float*)d_in[2];
    const float* benc = (const float*)d_in[3];
    const float* W1   = (const float*)d_in[4];
    const float* b1   = (const float*)d_in[5];
    const float* W2   = (const float*)d_in[6];
    const float* b2   = (const float*)d_in[7];
    const float* W3   = (const float*)d_in[8];
    const float* b3   = (const float*)d_in[9];
    const float* Wh1  = (const float*)d_in[10];
    const float* bh1  = (const float*)d_in[11];
    const float* Wh2  = (const float*)d_in[12];
    const float* bh2  = (const float*)d_in[13];
    const float* Wh3  = (const float*)d_in[14];
    const float* bh3  = (const float*)d_in[15];
    const float* Wh4  = (const float*)d_in[16];
    const float* bh4  = (const float*)d_in[17];
    float* out = (float*)d_out;

    char* ws = (char*)d_ws;
    // workspace layout (bytes)
    double* stats = (double*)ws;                          // 3 x B x {sum,sumsq}
    _Float16* w1h = (_Float16*)(ws + 8192);               // 512*384*2   = 393216
    _Float16* w1l = (_Float16*)(ws + 401408);
    _Float16* w2h = (_Float16*)(ws + 794624);             // 256*1536*2  = 786432
    _Float16* w2l = (_Float16*)(ws + 1581056);
    _Float16* w3h = (_Float16*)(ws + 2367488);            // 128*768*2   = 196608
    _Float16* w3l = (_Float16*)(ws + 2564096);
    const size_t offA = 2762752;                          // t0 / t2 region
    const size_t offB = offA + (size_t)B_ * MM_ * C2_ * sizeof(float);  // t1 / t3
    float* t0 = (float*)(ws + offA);                      // (B,1025,128) padded
    float* t1 = (float*)(ws + offB);
    float* t2 = (float*)(ws + offA);
    float* t3 = (float*)(ws + offB);

    hipMemsetAsync(stats, 0, 3 * B_ * 2 * sizeof(double), stream);

    wprep_kernel<CH0_, 128, C1_><<<dim3((C1_ * 384 + 255) / 256), dim3(256), 0, stream>>>(W1, w1h, w1l);
    wprep_kernel<C1_,  C1_, C2_><<<dim3((C2_ * 1536 + 255) / 256), dim3(256), 0, stream>>>(W2, w2h, w2l);
    wprep_kernel<C2_,  C2_, C3_><<<dim3((C3_ * 768 + 255) / 256), dim3(256), 0, stream>>>(W3, w3h, w3l);

    enc_kernel<<<dim3(17, 2, B_), dim3(256), 0, stream>>>(x, Wenc, benc, t0);

    conv_mfma_kernel<C0P_, C1_, false><<<dim3(4 * 4 * B_), dim3(512), 0, stream>>>(
        t0, idx, w1h, w1l, b1, nullptr, 1, stats + 0, t1);

    conv_mfma_kernel<C1_, C2_, true><<<dim3(4 * 2 * B_), dim3(512), 0, stream>>>(
        t1, idx, w2h, w2l, b2, stats + 0, C1_ * MM_, stats + 2 * B_, t2);

    conv_mfma_kernel<C2_, C3_, true><<<dim3(4 * 1 * B_), dim3(512), 0, stream>>>(
        t2, idx, w3h, w3l, b3, stats + 2 * B_, C2_ * MM_, stats + 4 * B_, t3);

    pool_head_kernel<<<dim3(B_), dim3(128), 0, stream>>>(
        t3, stats + 4 * B_, Wh1, bh1, Wh2, bh2, Wh3, bh3, Wh4, bh4, out);
}

// Round 4
// 894.037 us; speedup vs baseline: 3.0047x; 1.0787x over previous
//
#include <hip/hip_runtime.h>
#include <hip/hip_bf16.h>
#include <math.h>

#define B_   128
#define FQ_  318
#define CH0_ 109
#define NN_  1024
#define MM_  1025
#define C1_  512
#define C2_  256
#define C3_  128
#define C0P_ 128   // t0 channel padding (109 -> 128)

typedef _Float16 f16x8 __attribute__((ext_vector_type(8)));
typedef float    f32x4 __attribute__((ext_vector_type(4)));

#define GLOAD_LDS16(g, l) __builtin_amdgcn_global_load_lds( \
    (const __attribute__((address_space(1))) void*)(g),     \
    (__attribute__((address_space(3))) void*)(l), 16, 0, 0)

// LDS chunk layout: rows of 32 f16 (64 B = 4 quads of 16 B), quad-XOR swizzle.
// off (f16 units) for logical (row, quad): row*32 + ((q ^ ((row>>1)&3)) << 3)
__device__ __forceinline__ int lds_qoff(int row, int q) {
    return row * 32 + (((q ^ ((row >> 1) & 3)) & 3) << 3);
}

// ---------------------------------------------------------------------------
// Encoder: t0[b, m, c] = sum_f x[b, f, m] * Wenc[c, f] + benc[c]
// t0 layout: (B, 1025, 128) node-major, channels padded 109->128 with zeros,
// row m==0 zeroed.
// ---------------------------------------------------------------------------
__global__ __launch_bounds__(256) void enc_kernel(
    const float* __restrict__ x, const float* __restrict__ Wenc,
    const float* __restrict__ benc, float* __restrict__ t0)
{
    __shared__ __align__(16) float Xs[16][68];
    __shared__ __align__(16) float WsT[16][68];

    const int tid = threadIdx.x;
    const int b  = blockIdx.z;
    const int m0 = blockIdx.x * 64;
    const int c0 = blockIdx.y * 64;
    const int txc = tid & 15;
    const int tym = tid >> 4;

    float acc[4][4];
#pragma unroll
    for (int i = 0; i < 4; ++i)
#pragma unroll
        for (int j = 0; j < 4; ++j) acc[i][j] = 0.f;

    const int ml = tid & 63;
    const int kq = tid >> 6;
    const int wl = tid & 15;
    const int wg = tid >> 4;

    for (int f0 = 0; f0 < FQ_; f0 += 16) {
#pragma unroll
        for (int i = 0; i < 4; ++i) {
            const int k = kq * 4 + i;
            const int f = f0 + k;
            const int m = m0 + ml;
            Xs[k][ml] = (f < FQ_ && m < MM_)
                        ? x[(size_t)b * FQ_ * MM_ + (size_t)f * MM_ + m] : 0.f;
        }
#pragma unroll
        for (int pass = 0; pass < 4; ++pass) {
            const int cl = pass * 16 + wg;
            const int f  = f0 + wl;
            WsT[wl][cl] = (c0 + cl < CH0_ && f < FQ_)
                          ? Wenc[(size_t)(c0 + cl) * FQ_ + f] : 0.f;
        }
        __syncthreads();
#pragma unroll
        for (int k = 0; k < 16; ++k) {
            const float4 a = *reinterpret_cast<const float4*>(&Xs[k][tym * 4]);
            const float4 w = *reinterpret_cast<const float4*>(&WsT[k][txc * 4]);
            const float av[4] = {a.x, a.y, a.z, a.w};
            const float wv[4] = {w.x, w.y, w.z, w.w};
#pragma unroll
            for (int i = 0; i < 4; ++i)
#pragma unroll
                for (int j = 0; j < 4; ++j)
                    acc[i][j] = fmaf(av[i], wv[j], acc[i][j]);
        }
        __syncthreads();
    }

#pragma unroll
    for (int i = 0; i < 4; ++i) {
        const int m = m0 + tym * 4 + i;
        if (m >= MM_) continue;
#pragma unroll
        for (int j = 0; j < 4; ++j) {
            const int c = c0 + txc * 4 + j;
            const bool valid = (m != 0) && (c < CH0_);
            const float v = valid ? (acc[i][j] + benc[c < CH0_ ? c : 0]) : 0.f;
            t0[((size_t)b * MM_ + m) * C0P_ + c] = v;
        }
    }
}

// ---------------------------------------------------------------------------
// Weight prep: reorder W (C_OUT, C_IN, 3) -> k-major Wr[o][kk*C_IN_PAD + c],
// split fp32 into f16 hi + f16 lo. Pad region (c >= C_IN) is zero.
// ---------------------------------------------------------------------------
template <int C_IN, int C_IN_PAD, int C_OUT>
__global__ __launch_bounds__(256) void wprep_kernel(
    const float* __restrict__ W, _Float16* __restrict__ Wh, _Float16* __restrict__ Wl)
{
    constexpr int KP = 3 * C_IN_PAD;
    const int id = blockIdx.x * 256 + threadIdx.x;
    if (id >= C_OUT * KP) return;
    const int o = id / KP, k = id - o * KP;
    const int kk = k / C_IN_PAD, c = k - kk * C_IN_PAD;
    const float v = (c < C_IN) ? W[((size_t)o * C_IN + c) * 3 + kk] : 0.f;
    const _Float16 h = (_Float16)v;
    Wh[id] = h;
    Wl[id] = (_Float16)(v - (float)h);
}

// ---------------------------------------------------------------------------
// MFMA gather-conv, split-f16 3-term, dbuf LDS, quad-XOR swizzle,
// W staged via global_load_lds (pre-swizzled global source, linear LDS dest).
// Block: 512 threads (8 waves = 4n x 2o), tile 256 nodes x OTILE out-channels.
// out[b, n+1, o] = inv_in * conv(relu(gather - mean_in)) + bias ; out[b,0,:]=0.
// ---------------------------------------------------------------------------
template <int C_IN_STRIDE, int C_OUT, int OTILE, bool NORM>
__global__ __launch_bounds__(512, 2) void conv_mfma_kernel(
    const float* __restrict__ tin, const int* __restrict__ idx,
    const _Float16* __restrict__ Wh, const _Float16* __restrict__ Wl,
    const float* __restrict__ bias,
    const double* __restrict__ stats_in, const int prev_count,
    double* __restrict__ stats_out, float* __restrict__ tout)
{
    constexpr int KP   = 3 * C_IN_STRIDE;
    constexpr int NC   = KP / 32;             // k-chunks
    constexpr int CPC  = C_IN_STRIDE / 32;    // chunks per child (pow2)
    constexpr int OTB  = C_OUT / OTILE;       // o-tiles
    constexpr int OF   = OTILE / 32;          // B frags per wave (o-dir)
    constexpr int WISS = OTILE / 128;         // W lds-load issues per wave
    static_assert(KP % 32 == 0 && (CPC & (CPC - 1)) == 0, "bad pad");
    static_assert(OTILE == 128 || OTILE == 256, "otile");

    __shared__ __align__(16) _Float16 GhS[2][256 * 32];
    __shared__ __align__(16) _Float16 GlS[2][256 * 32];
    __shared__ __align__(16) _Float16 WhS[2][OTILE * 32];
    __shared__ __align__(16) _Float16 WlS[2][OTILE * 32];
    __shared__ int idxs[768];
    __shared__ float s_norm[2];
    __shared__ double redS[8], redQ[8];

    const int tid = threadIdx.x;

    // XCD-aware bijective swizzle (nwg % 8 == 0 for all instantiations)
    const int nwg  = 4 * OTB * B_;
    const int cpx  = nwg >> 3;
    const int orig = blockIdx.x;
    const int swz  = (orig & 7) * cpx + (orig >> 3);
    const int b    = swz / (4 * OTB);
    const int rr   = swz - b * (4 * OTB);
    const int mt   = rr / OTB;
    const int ot   = rr - mt * OTB;
    const int n_base = mt * 256;
    const int o0     = ot * OTILE;

    {
        const int* ip = idx + (size_t)b * (3 * NN_) + n_base * 3;
        idxs[tid] = ip[tid];
        if (tid < 256) idxs[512 + tid] = ip[512 + tid];
    }
    if (NORM && tid == 0) {
        const double s = stats_in[2 * b], q = stats_in[2 * b + 1];
        const double meand = s / prev_count;
        const double var   = (q - s * s / prev_count) / (prev_count - 1);
        s_norm[0] = (float)meand;
        s_norm[1] = (float)(1.0 / (sqrt(var) + 1e-5));
    }
    __syncthreads();
    const float mean = NORM ? s_norm[0] : 0.f;
    const float inv  = NORM ? s_norm[1] : 1.f;

    const float* tb = tin + (size_t)b * MM_ * C_IN_STRIDE;
    const int gn = tid >> 1, gh = tid & 1;    // gather: 256 rows x 2 halves of 16
    const int lane = tid & 63, wid = tid >> 6;
    const int wr = wid >> 1, wc = wid & 1;
    const int lrow = lane & 15, lkg = lane >> 4;

    float4 gv[4];

    auto load_chunk = [&](int ch) {
        const int kk = ch / CPC;
        const int c0 = (ch & (CPC - 1)) * 32;
        const int r  = idxs[gn * 3 + kk];
        const float* src = tb + (size_t)r * C_IN_STRIDE + c0 + gh * 16;
#pragma unroll
        for (int q = 0; q < 4; ++q)
            gv[q] = *reinterpret_cast<const float4*>(src + q * 4);
    };

    // W: per wave, WISS issues of 16 rows x 64 B; LDS linear, source pre-swizzled
    auto stageW = [&](int ch, int buf) {
#pragma unroll
        for (int s = 0; s < WISS; ++s) {
            const int baseRow = (wid * WISS + s) * 16;
            const int row  = baseRow + (lane >> 2);
            const int qp   = lane & 3;
            const int qsrc = qp ^ ((row >> 1) & 3);
            const size_t goff = (size_t)(o0 + row) * KP + ch * 32 + qsrc * 8;
            GLOAD_LDS16(Wh + goff, &WhS[buf][baseRow * 32]);
            GLOAD_LDS16(Wl + goff, &WlS[buf][baseRow * 32]);
        }
    };

    auto store_chunk = [&](int buf) {
        float vv[16];
#pragma unroll
        for (int q = 0; q < 4; ++q) {
            vv[q * 4 + 0] = gv[q].x; vv[q * 4 + 1] = gv[q].y;
            vv[q * 4 + 2] = gv[q].z; vv[q * 4 + 3] = gv[q].w;
        }
        _Float16 hh[16], ll[16];
#pragma unroll
        for (int e = 0; e < 16; ++e) {
            float v = vv[e];
            if (NORM) v = fmaxf(0.f, v - mean);   // inv folded into epilogue
            const _Float16 h = (_Float16)v;
            hh[e] = h;
            ll[e] = (_Float16)(v - (float)h);
        }
#pragma unroll
        for (int hf = 0; hf < 2; ++hf) {          // logical quads 2gh, 2gh+1
            f16x8 vh, vl;
#pragma unroll
            for (int e = 0; e < 8; ++e) { vh[e] = hh[hf * 8 + e]; vl[e] = ll[hf * 8 + e]; }
            const int off = lds_qoff(gn, 2 * gh + hf);
            *reinterpret_cast<f16x8*>(&GhS[buf][off]) = vh;
            *reinterpret_cast<f16x8*>(&GlS[buf][off]) = vl;
        }
    };

    f32x4 acc[4][OF];
#pragma unroll
    for (int i = 0; i < 4; ++i)
#pragma unroll
        for (int j = 0; j < OF; ++j) acc[i][j] = (f32x4){0.f, 0.f, 0.f, 0.f};

    auto compute_chunk = [&](int buf) {
        f16x8 ah[4], al[4];
#pragma unroll
        for (int f = 0; f < 4; ++f) {
            const int ar  = wr * 64 + f * 16 + lrow;
            const int off = lds_qoff(ar, lkg);
            ah[f] = *reinterpret_cast<const f16x8*>(&GhS[buf][off]);
            al[f] = *reinterpret_cast<const f16x8*>(&GlS[buf][off]);
        }
        __builtin_amdgcn_s_setprio(1);
#pragma unroll
        for (int j = 0; j < OF; ++j) {
            const int br  = wc * (OTILE / 2) + j * 16 + lrow;
            const int off = lds_qoff(br, lkg);
            const f16x8 bh = *reinterpret_cast<const f16x8*>(&WhS[buf][off]);
            const f16x8 bl = *reinterpret_cast<const f16x8*>(&WlS[buf][off]);
#pragma unroll
            for (int i = 0; i < 4; ++i)
                acc[i][j] = __builtin_amdgcn_mfma_f32_16x16x32_f16(ah[i], bh, acc[i][j], 0, 0, 0);
#pragma unroll
            for (int i = 0; i < 4; ++i)
                acc[i][j] = __builtin_amdgcn_mfma_f32_16x16x32_f16(al[i], bh, acc[i][j], 0, 0, 0);
#pragma unroll
            for (int i = 0; i < 4; ++i)
                acc[i][j] = __builtin_amdgcn_mfma_f32_16x16x32_f16(ah[i], bl, acc[i][j], 0, 0, 0);
        }
        __builtin_amdgcn_s_setprio(0);
    };

    // pipeline: dbuf LDS, one barrier per chunk
    stageW(0, 0);
    load_chunk(0);
    store_chunk(0);
    __syncthreads();
    for (int ch = 0; ch < NC; ++ch) {
        const int buf = ch & 1;
        if (ch + 1 < NC) { stageW(ch + 1, buf ^ 1); load_chunk(ch + 1); }
        compute_chunk(buf);
        if (ch + 1 < NC) store_chunk(buf ^ 1);
        __syncthreads();
    }

    // epilogue: scale by inv, add bias, store raw fp32, stats
    float bv[OF];
#pragma unroll
    for (int j = 0; j < OF; ++j) bv[j] = bias[o0 + wc * (OTILE / 2) + j * 16 + lrow];

    double s = 0.0, q = 0.0;
    float* outb = tout + (size_t)b * MM_ * C_OUT;
#pragma unroll
    for (int i = 0; i < 4; ++i) {
        const int nrow = n_base + wr * 64 + i * 16 + lkg * 4;
#pragma unroll
        for (int j = 0; j < OF; ++j) {
            const int o = o0 + wc * (OTILE / 2) + j * 16 + lrow;
#pragma unroll
            for (int r = 0; r < 4; ++r) {
                const float v = fmaf(acc[i][j][r], inv, bv[j]);
                outb[(size_t)(nrow + r + 1) * C_OUT + o] = v;
                s += (double)v;
                q += (double)v * (double)v;
            }
        }
    }
    if (mt == 0) {
        for (int o = tid; o < OTILE; o += 512) outb[o0 + o] = 0.f;  // null row
    }

#pragma unroll
    for (int off = 32; off > 0; off >>= 1) {
        s += __shfl_down(s, off);
        q += __shfl_down(q, off);
    }
    if (lane == 0) { redS[wid] = s; redQ[wid] = q; }
    __syncthreads();
    if (tid == 0) {
        double ts = 0.0, tq = 0.0;
#pragma unroll
        for (int w = 0; w < 8; ++w) { ts += redS[w]; tq += redQ[w]; }
        atomicAdd(&stats_out[2 * b], ts);
        atomicAdd(&stats_out[2 * b + 1], tq);
    }
}

// ---------------------------------------------------------------------------
// Fused: normalize t3 on the fly, max-pool over 1025 nodes, then the MLP head.
// 1024 threads: (o = tid&127, mg = tid>>7) -> 8-way parallel over nodes.
// ---------------------------------------------------------------------------
__global__ __launch_bounds__(1024) void pool_head_kernel(
    const float* __restrict__ t3, const double* __restrict__ stats3,
    const float* __restrict__ Wh1, const float* __restrict__ bh1,
    const float* __restrict__ Wh2, const float* __restrict__ bh2,
    const float* __restrict__ Wh3, const float* __restrict__ bh3,
    const float* __restrict__ Wh4, const float* __restrict__ bh4,
    float* __restrict__ out)
{
    __shared__ float red[8][128];
    __shared__ float hs[128], h1s[128], h2s[64], h3s[32];
    const int b = blockIdx.x;
    const int o = threadIdx.x & 127, mg = threadIdx.x >> 7;

    const double ssum = stats3[2 * b], ssq = stats3[2 * b + 1];
    const double cnt  = (double)C3_ * (double)MM_;
    const double meand = ssum / cnt;
    const double var   = (ssq - ssum * ssum / cnt) / (cnt - 1.0);
    const float mean = (float)meand;
    const float inv  = (float)(1.0 / (sqrt(var) + 1e-5));

    const float* tb = t3 + (size_t)b * MM_ * C3_;
    float best = 0.f;   // relu'd values are >= 0
    for (int m = mg; m < MM_; m += 8) {
        const float v = fmaxf(0.f, (tb[(size_t)m * C3_ + o] - mean) * inv);
        best = fmaxf(best, v);
    }
    red[mg][o] = best;
    __syncthreads();

    const int t = threadIdx.x;
    if (t < 128) {
        float h = red[0][t];
#pragma unroll
        for (int g = 1; g < 8; ++g) h = fmaxf(h, red[g][t]);
        hs[t] = h;
    }
    __syncthreads();

    if (t < 128) {
        float a1 = bh1[t];
        for (int i = 0; i < 128; ++i) a1 = fmaf(Wh1[t * 128 + i], hs[i], a1);
        h1s[t] = fmaxf(a1, 0.f);
    }
    __syncthreads();

    if (t < 64) {
        float a2 = bh2[t];
        for (int i = 0; i < 128; ++i) a2 = fmaf(Wh2[t * 128 + i], h1s[i], a2);
        h2s[t] = fmaxf(a2, 0.f);
    }
    __syncthreads();

    if (t < 32) {
        float a3 = bh3[t];
        for (int i = 0; i < 64; ++i) a3 = fmaf(Wh3[t * 64 + i], h2s[i], a3);
        h3s[t] = fmaxf(a3, 0.f);
    }
    __syncthreads();

    if (t == 0) {
        float a4 = bh4[0];
        for (int i = 0; i < 32; ++i) a4 = fmaf(Wh4[i], h3s[i], a4);
        out[b] = a4;
    }
}

// ---------------------------------------------------------------------------
extern "C" void kernel_launch(void* const* d_in, const int* in_sizes, int n_in,
                              void* d_out, int out_size, void* d_ws, size_t ws_size,
                              hipStream_t stream)
{
    const float* x    = (const float*)d_in[0];
    const int*   idx  = (const int*)d_in[1];
    const float* Wenc = (const float*)d_in[2];
    const float* benc = (const float*)d_in[3];
    const float* W1   = (const float*)d_in[4];
    const float* b1   = (const float*)d_in[5];
    const float* W2   = (const float*)d_in[6];
    const float* b2   = (const float*)d_in[7];
    const float* W3   = (const float*)d_in[8];
    const float* b3   = (const float*)d_in[9];
    const float* Wh1  = (const float*)d_in[10];
    const float* bh1  = (const float*)d_in[11];
    const float* Wh2  = (const float*)d_in[12];
    const float* bh2  = (const float*)d_in[13];
    const float* Wh3  = (const float*)d_in[14];
    const float* bh3  = (const float*)d_in[15];
    const float* Wh4  = (const float*)d_in[16];
    const float* bh4  = (const float*)d_in[17];
    float* out = (float*)d_out;

    char* ws = (char*)d_ws;
    double* stats = (double*)ws;                          // 3 x B x {sum,sumsq}
    _Float16* w1h = (_Float16*)(ws + 8192);               // 512*384*2   = 393216
    _Float16* w1l = (_Float16*)(ws + 401408);
    _Float16* w2h = (_Float16*)(ws + 794624);             // 256*1536*2  = 786432
    _Float16* w2l = (_Float16*)(ws + 1581056);
    _Float16* w3h = (_Float16*)(ws + 2367488);            // 128*768*2   = 196608
    _Float16* w3l = (_Float16*)(ws + 2564096);
    const size_t offA = 2762752;                          // t0 / t2 region
    const size_t offB = offA + (size_t)B_ * MM_ * C2_ * sizeof(float);  // t1 / t3
    float* t0 = (float*)(ws + offA);                      // (B,1025,128) padded
    float* t1 = (float*)(ws + offB);
    float* t2 = (float*)(ws + offA);
    float* t3 = (float*)(ws + offB);

    hipMemsetAsync(stats, 0, 3 * B_ * 2 * sizeof(double), stream);

    wprep_kernel<CH0_, 128, C1_><<<dim3((C1_ * 384 + 255) / 256), dim3(256), 0, stream>>>(W1, w1h, w1l);
    wprep_kernel<C1_,  C1_, C2_><<<dim3((C2_ * 1536 + 255) / 256), dim3(256), 0, stream>>>(W2, w2h, w2l);
    wprep_kernel<C2_,  C2_, C3_><<<dim3((C3_ * 768 + 255) / 256), dim3(256), 0, stream>>>(W3, w3h, w3l);

    enc_kernel<<<dim3(17, 2, B_), dim3(256), 0, stream>>>(x, Wenc, benc, t0);

    conv_mfma_kernel<C0P_, C1_, 256, false><<<dim3(4 * 2 * B_), dim3(512), 0, stream>>>(
        t0, idx, w1h, w1l, b1, nullptr, 1, stats + 0, t1);

    conv_mfma_kernel<C1_, C2_, 256, true><<<dim3(4 * 1 * B_), dim3(512), 0, stream>>>(
        t1, idx, w2h, w2l, b2, stats + 0, C1_ * MM_, stats + 2 * B_, t2);

    conv_mfma_kernel<C2_, C3_, 128, true><<<dim3(4 * 1 * B_), dim3(512), 0, stream>>>(
        t2, idx, w3h, w3l, b3, stats + 2 * B_, C2_ * MM_, stats + 4 * B_, t3);

    pool_head_kernel<<<dim3(B_), dim3(1024), 0, stream>>>(
        t3, stats + 4 * B_, Wh1, bh1, Wh2, bh2, Wh3, bh3, Wh4, bh4, out);
}